// Round 1
// baseline (414.868 us; speedup 1.0000x reference)
//
#include <hip/hip_runtime.h>

// ShiftConvGeneral: hard-softmax(3x3 weight) is one-hot -> depthwise conv
// collapses to a zero-padded shifted copy of x by (sh, sw) = argmax(|w|) - 1.
//
// x: (16, 64, 256, 256) fp32. Treat as 1024 images of 256x256.
// Block = 256 threads: 4 rows per block, 64 lanes/row, float4 (16B) per lane.
// Grid = 1024*256/4 = 65536 blocks. Memory-bound: 64 MiB in + 64 MiB out.

__global__ __launch_bounds__(256) void ShiftConvGeneral_65738769433039_kernel(
    const float* __restrict__ x, const float* __restrict__ w,
    float* __restrict__ out) {
    __shared__ int s_sh, s_sw;
    if (threadIdx.x == 0) {
        // argmax of |w[0..8]|, first occurrence wins (matches jnp.argmax)
        float best = -1.0f;
        int bi = 0;
#pragma unroll
        for (int i = 0; i < 9; ++i) {
            float a = fabsf(w[i]);
            if (a > best) { best = a; bi = i; }
        }
        s_sh = bi / 3 - 1;   // row shift in {-1,0,1}
        s_sw = bi % 3 - 1;   // col shift in {-1,0,1}
    }
    __syncthreads();
    const int sh = s_sh;
    const int sw = s_sw;

    const int tid  = threadIdx.x;
    const int lane = tid & 63;                      // lane within the row
    const int row_global = blockIdx.x * 4 + (tid >> 6);
    const int h   = row_global & 255;
    const int img = row_global >> 8;                // (b*64 + c)
    const int c0  = lane << 2;                      // first of 4 output cols

    const int hin = h + sh;
    float4 v = make_float4(0.f, 0.f, 0.f, 0.f);
    if ((unsigned)hin < 256u) {
        const float* in_row = x + ((size_t)img << 16) + ((size_t)hin << 8);
        if (sw == 0) {
            // aligned fast path (wave-uniform branch)
            v = *(const float4*)(in_row + c0);
        } else {
            float r[4];
#pragma unroll
            for (int j = 0; j < 4; ++j) {
                int cc = c0 + sw + j;
                r[j] = ((unsigned)cc < 256u) ? in_row[cc] : 0.f;
            }
            v = make_float4(r[0], r[1], r[2], r[3]);
        }
    }
    float4* orow = (float4*)(out + ((size_t)row_global << 8));
    orow[lane] = v;
}

extern "C" void kernel_launch(void* const* d_in, const int* in_sizes, int n_in,
                              void* d_out, int out_size, void* d_ws, size_t ws_size,
                              hipStream_t stream) {
    const float* x = (const float*)d_in[0];     // (16,64,256,256) fp32
    const float* w = (const float*)d_in[1];     // (1,1,3,3) fp32
    float* out = (float*)d_out;                 // (16,64,256,256) fp32

    const int total_rows = 16 * 64 * 256;       // 262144 rows of 256 floats
    const int blocks = total_rows / 4;          // 65536
    ShiftConvGeneral_65738769433039_kernel<<<blocks, 256, 0, stream>>>(x, w, out);
}